// Round 6
// baseline (75.499 us; speedup 1.0000x reference)
//
#include <hip/hip_runtime.h>

// Problem constants (from reference): B=128, T=4096, N=16, D=3
#define BB 128
#define TT 4096
#define NN 16
#define DD 3
#define TPB 256
#define GROUPS (TPB/NN)            // 16 slabs per block
#define NBLK ((BB*TT)/GROUPS)      // 32768 blocks

// 12-byte aggregate, 4-B aligned -> compiler emits global_load_dwordx3
struct f3 { float a, b, c; };

// Lane-parallel analytic inverse of the Jacobi matrix (no LDS, no barriers):
//   c_k = m_k / M_k (prefix sum of masses), c_0 := 1
//   r_k = x0 + x_k - sum_{i=k}^{N-1} c_i x_i      (uniform for all k with c_0=1)
// 16 lanes per slab (one k per lane, 3 d-components per lane).
// R6 ablation: PLAIN stores (R4 used nontemporal) — everything else identical.
__global__ __launch_bounds__(TPB) void jacobi_to_cartesian_kernel(
    const float* __restrict__ m,
    const float* __restrict__ qj,
    const float* __restrict__ vj,
    float* __restrict__ outq,
    float* __restrict__ outv)
{
    const int t = threadIdx.x;
    const int l = t & (NN - 1);                       // k index within slab
    const size_t slab = (size_t)blockIdx.x * GROUPS + (t >> 4);
    const int b = (int)(slab >> 12);                  // slab / TT (TT=4096)

    // c_l = m_l / M_l via width-16 inclusive prefix scan (DPP row ops)
    const float mk = m[b * NN + l];
    float M = mk;
    #pragma unroll
    for (int d = 1; d < NN; d <<= 1) {
        float tmp = __shfl_up(M, d, NN);
        if (l >= d) M += tmp;
    }
    const float c = (l == 0) ? 1.0f : mk / M;

    const size_t base = slab * (size_t)(NN * DD) + (size_t)l * DD;

    #pragma unroll
    for (int which = 0; which < 2; ++which) {
        const float* __restrict__ src = (which ? vj : qj) + base;
        float*       __restrict__ dst = (which ? outv : outq) + base;

        const f3 xv = *(const f3*)src;                // dwordx3, 768B/wave contiguous

        // y_l = c_l * x_l ; suffix-scan within the 16-lane group
        float y0 = c * xv.a, y1 = c * xv.b, y2 = c * xv.c;
        #pragma unroll
        for (int d = 1; d < NN; d <<= 1) {
            float t0 = __shfl_down(y0, d, NN);
            float t1 = __shfl_down(y1, d, NN);
            float t2 = __shfl_down(y2, d, NN);
            if (l + d < NN) { y0 += t0; y1 += t1; y2 += t2; }
        }

        // x0 = Jacobi coordinate 0 (the COM) = group's lane-0 value
        const float x00 = __shfl(xv.a, 0, NN);
        const float x01 = __shfl(xv.b, 0, NN);
        const float x02 = __shfl(xv.c, 0, NN);

        // Plain stores: let L2/L3 allocate + write-combine normally
        dst[0] = x00 + xv.a - y0;
        dst[1] = x01 + xv.b - y1;
        dst[2] = x02 + xv.c - y2;
    }
}

extern "C" void kernel_launch(void* const* d_in, const int* in_sizes, int n_in,
                              void* d_out, int out_size, void* d_ws, size_t ws_size,
                              hipStream_t stream) {
    const float* m  = (const float*)d_in[0];
    const float* qj = (const float*)d_in[1];
    const float* vj = (const float*)d_in[2];

    float* outq = (float*)d_out;
    float* outv = outq + (size_t)BB * TT * NN * DD;

    jacobi_to_cartesian_kernel<<<NBLK, TPB, 0, stream>>>(m, qj, vj, outq, outv);
}

// Round 7
// 61.755 us; speedup vs baseline: 1.2226x; 1.2226x over previous
//
#include <hip/hip_runtime.h>

// Problem constants (from reference): B=128, T=4096, N=16, D=3
#define BB 128
#define TT 4096
#define NN 16
#define DD 3
#define TPB 256
#define GROUPS (TPB/NN)            // 16 slabs per block
#define NBLK ((BB*TT)/GROUPS)      // 32768 blocks

// 12-byte aggregate, 4-B aligned -> compiler emits global_load_dwordx3
struct f3 { float a, b, c; };

// Lane-parallel analytic inverse of the Jacobi matrix (no LDS, no barriers):
//   c_k = m_k / M_k (prefix sum of masses), c_0 := 1
//   r_k = x0 + x_k - sum_{i=k}^{N-1} c_i x_i      (uniform for all k with c_0=1)
// 16 lanes per slab (one k per lane, 3 d-components per lane).
// BEST CONFIG (R4): nontemporal stores are +24% — they keep the 201 MB input
// set resident in L3 by not allocating the output stream (R6 ablation).
__global__ __launch_bounds__(TPB) void jacobi_to_cartesian_kernel(
    const float* __restrict__ m,
    const float* __restrict__ qj,
    const float* __restrict__ vj,
    float* __restrict__ outq,
    float* __restrict__ outv)
{
    const int t = threadIdx.x;
    const int l = t & (NN - 1);                       // k index within slab
    const size_t slab = (size_t)blockIdx.x * GROUPS + (t >> 4);
    const int b = (int)(slab >> 12);                  // slab / TT (TT=4096)

    // c_l = m_l / M_l via width-16 inclusive prefix scan (DPP row ops)
    const float mk = m[b * NN + l];
    float M = mk;
    #pragma unroll
    for (int d = 1; d < NN; d <<= 1) {
        float tmp = __shfl_up(M, d, NN);
        if (l >= d) M += tmp;
    }
    const float c = (l == 0) ? 1.0f : mk / M;

    const size_t base = slab * (size_t)(NN * DD) + (size_t)l * DD;

    #pragma unroll
    for (int which = 0; which < 2; ++which) {
        const float* __restrict__ src = (which ? vj : qj) + base;
        float*       __restrict__ dst = (which ? outv : outq) + base;

        const f3 xv = *(const f3*)src;                // dwordx3, 768B/wave contiguous

        // y_l = c_l * x_l ; suffix-scan within the 16-lane group
        float y0 = c * xv.a, y1 = c * xv.b, y2 = c * xv.c;
        #pragma unroll
        for (int d = 1; d < NN; d <<= 1) {
            float t0 = __shfl_down(y0, d, NN);
            float t1 = __shfl_down(y1, d, NN);
            float t2 = __shfl_down(y2, d, NN);
            if (l + d < NN) { y0 += t0; y1 += t1; y2 += t2; }
        }

        // x0 = Jacobi coordinate 0 (the COM) = group's lane-0 value
        const float x00 = __shfl(xv.a, 0, NN);
        const float x01 = __shfl(xv.b, 0, NN);
        const float x02 = __shfl(xv.c, 0, NN);

        __builtin_nontemporal_store(x00 + xv.a - y0, dst + 0);
        __builtin_nontemporal_store(x01 + xv.b - y1, dst + 1);
        __builtin_nontemporal_store(x02 + xv.c - y2, dst + 2);
    }
}

extern "C" void kernel_launch(void* const* d_in, const int* in_sizes, int n_in,
                              void* d_out, int out_size, void* d_ws, size_t ws_size,
                              hipStream_t stream) {
    const float* m  = (const float*)d_in[0];
    const float* qj = (const float*)d_in[1];
    const float* vj = (const float*)d_in[2];

    float* outq = (float*)d_out;
    float* outv = outq + (size_t)BB * TT * NN * DD;

    jacobi_to_cartesian_kernel<<<NBLK, TPB, 0, stream>>>(m, qj, vj, outq, outv);
}